// Round 13
// baseline (470.375 us; speedup 1.0000x reference)
//
#include <hip/hip_runtime.h>
#include <stdint.h>

typedef uint16_t u16;
typedef uint32_t u32;
typedef uint64_t u64;

#define TPB   256
#define TILE  2048      // scan granularity (TPB*8)
#define RADIX 512
#define RBITS 9
#define STILE 4096      // sort tile (2^12)
#define GSPB  256       // genK spheres per block (2 per wave concurrently)
#define WIN   6         // genK pass-0 hist window (block spans <=5 tiles +1 guard)

#define SCTPB 512       // scatter threads (8 waves)
#define NWAVE 8
#define SSLOT 8         // STILE / SCTPB
#define NXCD  8

__device__ __forceinline__ int clampi(int v, int lo, int hi){ return v < lo ? lo : (v > hi ? hi : v); }

__device__ __forceinline__ u32 expand10(u32 x){
  x &= 1023u;
  x = (x | (x << 16)) & 0x030000FFu;
  x = (x | (x << 8))  & 0x0300F00Fu;
  x = (x | (x << 4))  & 0x030C30C3u;
  x = (x | (x << 2))  & 0x09249249u;
  return x;
}

struct Box { int a0,a1,a2,e0,e1,e2,nv; };
__device__ __forceinline__ Box boxOf(int i, const float* mn, const float* mx,
                                     float g0, float g1, float g2, float vs, int gs){
  Box b;
  int a0 = clampi((int)floorf((mn[3*i+0] - g0) / vs), 0, gs-1);
  int a1 = clampi((int)floorf((mn[3*i+1] - g1) / vs), 0, gs-1);
  int a2 = clampi((int)floorf((mn[3*i+2] - g2) / vs), 0, gs-1);
  int b0 = clampi((int)floorf((mx[3*i+0] - g0) / vs), 0, gs-1);
  int b1 = clampi((int)floorf((mx[3*i+1] - g1) / vs), 0, gs-1);
  int b2 = clampi((int)floorf((mx[3*i+2] - g2) / vs), 0, gs-1);
  b.a0=a0; b.a1=a1; b.a2=a2;
  b.e0=b0-a0+1; b.e1=b1-a1+1; b.e2=b2-a2+1;
  b.nv = b.e0*b.e1*b.e2;
  return b;
}

// counts, oversized flags, and packed box encoding with div magics
__global__ void countK(const float* mn, const float* mx, const float* gmin,
                       const float* vs_p, const int* gs_p, const int* T_p,
                       u32* counts, int* out_ovr, uint4* boxEnc, int M){
  int i = blockIdx.x * TPB + threadIdx.x;
  if (i >= M) return;
  float vs = vs_p[0]; int gs = gs_p[0]; int T = T_p[0];
  Box b = boxOf(i, mn, mx, gmin[0], gmin[1], gmin[2], vs, gs);
  int ovr = b.nv > T;
  counts[i] = ovr ? 0u : (u32)b.nv;
  out_ovr[i] = ovr;
  u32 nvq = ovr ? 0u : (u32)b.nv;
  uint4 be;
  be.x = (u32)b.a0 | ((u32)b.a1 << 10) | ((u32)b.a2 << 20);
  be.y = (u32)b.e1 | ((u32)b.e2 << 7) | (nvq << 14);
  be.z = 65535u / (u32)b.e1 + 1u;   // mEy = ceil(2^16/e1)
  be.w = 65535u / (u32)b.e2 + 1u;   // mEz = ceil(2^16/e2)
  boxEnc[i] = be;
}

__global__ void scanAK(const u32* counts, int* out_off, u32* blockSums, int M){
  __shared__ u32 s[TPB];
  int b = blockIdx.x, t = threadIdx.x;
  int base = b * TILE + t * 8;
  u32 incl[8]; u32 run = 0;
  #pragma unroll
  for (int j = 0; j < 8; ++j){
    int g = base + j;
    u32 v = (g < M) ? counts[g] : 0u;
    run += v; incl[j] = run;
  }
  s[t] = run;
  __syncthreads();
  for (int o = 1; o < TPB; o <<= 1){
    u32 x = (t >= o) ? s[t-o] : 0u;
    __syncthreads();
    s[t] += x;
    __syncthreads();
  }
  u32 tbase = s[t] - run;
  #pragma unroll
  for (int j = 0; j < 8; ++j){
    int g = base + j;
    if (g < M) out_off[g+1] = (int)(tbase + incl[j]);
  }
  if (t == TPB-1) blockSums[b] = s[TPB-1];
}

__global__ void scanBK(u32* blockSums, int nb){
  __shared__ u32 s[TPB];
  int t = threadIdx.x;
  u32 run = 0;
  int nch = (nb + TPB - 1) / TPB;
  for (int c = 0; c < nch; ++c){
    int i = c * TPB + t;
    u32 v = (i < nb) ? blockSums[i] : 0u;
    s[t] = v;
    __syncthreads();
    for (int o = 1; o < TPB; o <<= 1){
      u32 x = (t >= o) ? s[t-o] : 0u;
      __syncthreads();
      s[t] += x;
      __syncthreads();
    }
    if (i < nb) blockSums[i] = run + s[t] - v;
    u32 tot = s[TPB-1];
    __syncthreads();
    run += tot;
  }
}

__global__ void scanCK(int* out_off, const u32* blockSums, int M, int* out_total){
  int b = blockIdx.x, t = threadIdx.x;
  u32 add = blockSums[b];
  int base = b * TILE + t * 8;
  #pragma unroll
  for (int j = 0; j < 8; ++j){
    int g = base + j;
    if (g < M){
      int v = out_off[g+1] + (int)add;
      out_off[g+1] = v;
      if (g == M-1) out_total[0] = v;
    }
  }
  if (b == 0 && t == 0) out_off[0] = 0;
}

// pure generator: half-wave (32 lanes) per sphere, zero division, coalesced
// stores; builds pass-0 per-tile hist via LDS window (hist0 pre-zeroed).
__global__ void genK(const uint4* __restrict__ boxEnc, const int* __restrict__ out_off,
                     u64* __restrict__ out, u32* hist0, int maxTiles, int M){
  __shared__ u32 winHist[WIN * RADIX];   // 12 KB
  __shared__ int stile0;
  int t = threadIdx.x;
  for (int i = t; i < WIN * RADIX; i += TPB) winHist[i] = 0;
  int sbase = blockIdx.x * GSPB;
  if (t == 0) stile0 = out_off[sbase] >> 12;
  __syncthreads();
  int tile0 = stile0;
  int lane = t & 63, wave = t >> 6;
  int half = lane >> 5, l32 = lane & 31;
  int slot = wave * 2 + half;          // 0..7
  for (int s0 = 0; s0 < GSPB; s0 += 8){
    int i = sbase + s0 + slot;
    if (i >= M) continue;
    uint4 be = boxEnc[i];
    int nv = (int)(be.y >> 14);
    if (nv == 0) continue;             // oversized or empty
    int ey = (int)(be.y & 127), ez = (int)((be.y >> 7) & 127);
    int a0 = (int)(be.x & 1023), a1 = (int)((be.x >> 10) & 1023), a2 = (int)(be.x >> 20);
    u32 mEy = be.z, mEz = be.w;
    int base = out_off[i];
    for (int k = l32; k < nv; k += 32){
      u32 q1 = ((u32)k * mEz) >> 16;           // k / ez   (exact, k<=63)
      int dz = k - (int)(q1 * (u32)ez);
      u32 q2 = (q1 * mEy) >> 16;               // q1 / ey  (exact)
      int dy = (int)q1 - (int)(q2 * (u32)ey);
      int dx = (int)q2;
      u32 m = (expand10((u32)(a0 + dx)) << 2) |
              (expand10((u32)(a1 + dy)) << 1) |
               expand10((u32)(a2 + dz));
      int pos = base + k;
      out[pos] = ((u64)m << 32) | (u32)i;
      u32 d0 = m & (RADIX - 1);
      int rel = (pos >> 12) - tile0;
      if ((unsigned)rel < WIN) atomicAdd(&winHist[(rel << 9) + d0], 1u);
      else atomicAdd(&hist0[(size_t)d0 * maxTiles + (pos >> 12)], 1u);
    }
  }
  __syncthreads();
  for (int idx = t; idx < WIN * RADIX; idx += TPB){
    u32 c = winHist[idx];
    if (c){
      int wnd = idx >> 9, d = idx & (RADIX - 1);
      atomicAdd(&hist0[(size_t)d * maxTiles + (tile0 + wnd)], c);
    }
  }
}

// per-tile histogram for passes 1,2 (reads hi words of packed u64, uint4 loads)
__global__ void histK(const u64* __restrict__ in, u32* hist,
                      const int* total_p, int maxTiles, int shift){
  __shared__ u32 cnt[RADIX];
  int tile = blockIdx.x, t = threadIdx.x;
  int total = *total_p;
  int numTiles = (total + STILE - 1) / STILE;
  if (tile >= numTiles) return;
  cnt[t] = 0; cnt[t + TPB] = 0;
  __syncthreads();
  int base = tile * STILE;
  if (base + STILE <= total){
    const uint4* k4 = (const uint4*)(in + base);   // 2 packed elems per uint4
    #pragma unroll
    for (int s = 0; s < 8; ++s){
      uint4 v = k4[s * TPB + t];
      atomicAdd(&cnt[(v.y >> shift) & (RADIX-1)], 1u);
      atomicAdd(&cnt[(v.w >> shift) & (RADIX-1)], 1u);
    }
  } else {
    const u32* hi = (const u32*)in;
    #pragma unroll
    for (int s = 0; s < 16; ++s){
      int j = base + s * TPB + t;
      if (j < total) atomicAdd(&cnt[(hi[2*j+1] >> shift) & (RADIX-1)], 1u);
    }
  }
  __syncthreads();
  for (int d = t; d < RADIX; d += TPB)
    hist[(size_t)d * maxTiles + tile] = cnt[d];
}

// per-digit running prefix over tiles (in place, base 0); emit per-digit total
__global__ void tileScanK(u32* hist, u32* digitTotal, const int* total_p, int maxTiles){
  __shared__ u32 s[TPB];
  int d = blockIdx.x, t = threadIdx.x;
  int total = *total_p;
  int numTiles = (total + STILE - 1) / STILE;
  u32 running = 0;
  int nch = (numTiles + TPB - 1) / TPB;
  for (int c = 0; c < nch; ++c){
    int i = c * TPB + t;
    u32 v = (i < numTiles) ? hist[(size_t)d * maxTiles + i] : 0u;
    s[t] = v;
    __syncthreads();
    for (int o = 1; o < TPB; o <<= 1){
      u32 x = (t >= o) ? s[t-o] : 0u;
      __syncthreads();
      s[t] += x;
      __syncthreads();
    }
    if (i < numTiles) hist[(size_t)d * maxTiles + i] = running + s[t] - v;
    u32 tot = s[TPB-1];
    __syncthreads();
    running += tot;
  }
  if (t == 0) digitTotal[d] = running;
}

// staged scatter: 8 waves, elements held in registers, direct scattered LDS
// store into tile-sorted stage[], linear LDS read -> coalesced run writes.
// Folds the 512-digit base scan in via a packed u64 scan (hi=digitTotal,
// lo=startS; lo sums <= 4096 so no carry into hi). stage[] is the scratch.
__global__ __launch_bounds__(SCTPB, 4)
void scatterK(const u64* __restrict__ in, u64* __restrict__ out,
              const u32* __restrict__ hist, const u32* __restrict__ digitTotal,
              const int* total_p, int maxTiles, int shift){
  __shared__ u64 stage[STILE];          // 32 KB  scan scratch, then tile-sorted elements
  __shared__ u16 wHist[NWAVE * RADIX];  // 8 KB   [wave][digit]
  __shared__ u32 startS[RADIX];         // 2 KB   tile-local exclusive digit starts
  __shared__ u32 baseS[RADIX];          // 2 KB   global digit bases for this tile

  int t = threadIdx.x;
  int total = *total_p;
  int numTiles = (total + STILE - 1) / STILE;

  // bijective XCD-chunked swizzle: consecutive tiles -> same XCD
  int bid = blockIdx.x;
  int q = numTiles / NXCD, r = numTiles % NXCD;
  int x = bid & (NXCD - 1), pos = bid >> 3;
  int cnt_x = q + (x < r ? 1 : 0);
  if (pos >= cnt_x) return;
  int tile = (x < r ? x * (q + 1) : r * (q + 1) + (x - r) * q) + pos;

  int lane = t & 63, wave = t >> 6;
  u64 lt = (1ull << lane) - 1ull;
  u16* wh = &wHist[wave << 9];

  for (int i = t; i < NWAVE * RADIX; i += SCTPB) wHist[i] = 0;
  __syncthreads();

  int tbase = tile * STILE;
  int cbase = tbase + (wave << 9);     // wave-private contiguous chunk of 512
  u64 relem[SSLOT];                    // elements in registers (static indices)
  u32 rrd[SSLOT];                      // (rankInWave<<16) | digit

  // Phase A: load + stable wave rank (order: wave, slot, lane == index order)
  #pragma unroll
  for (int s = 0; s < SSLOT; ++s){
    int idx = cbase + (s << 6) + lane;
    bool valid = idx < total;
    u64 e = valid ? in[idx] : 0ull;
    relem[s] = e;
    int d = (int)(((u32)(e >> 32)) >> shift) & (RADIX - 1);
    u64 mask = __ballot(valid);
    #pragma unroll
    for (int b = 0; b < RBITS; ++b){
      u64 bal = __ballot((d >> b) & 1);
      mask &= ((d >> b) & 1) ? bal : ~bal;
    }
    u32 lr = (u32)__popcll(mask & lt);
    u32 old = valid ? (u32)wh[d] : 0u;
    if (valid && ((mask & lt) == 0ull)) wh[d] = (u16)(old + (u32)__popcll(mask));
    rrd[s] = ((old + lr) << 16) | (u32)d;
  }
  __syncthreads();

  // Phase B1: combine 8 wave hists (thread t <-> digit t; SCTPB == RADIX)
  u32 tileCnt;
  {
    int d = t;
    u32 run = 0;
    #pragma unroll
    for (int wv = 0; wv < NWAVE; ++wv){
      u32 cc = wHist[(wv << 9) + d];
      wHist[(wv << 9) + d] = (u16)run;
      run += cc;
    }
    tileCnt = run;
  }
  __syncthreads();

  // Phase B2: packed exclusive scan over digits: hi=digitTotal, lo=tile count.
  {
    u64 v = ((u64)digitTotal[t] << 32) | (u64)tileCnt;
    stage[t] = v;
    __syncthreads();
    for (int o = 1; o < RADIX; o <<= 1){
      u64 xv = (t >= o) ? stage[t-o] : 0ull;
      __syncthreads();
      stage[t] += xv;
      __syncthreads();
    }
    u64 excl = stage[t] - v;
    __syncthreads();                    // all scan reads done before stage reuse
    startS[t] = (u32)excl;                                   // tile-local start
    baseS[t]  = (u32)(excl >> 32) + hist[(size_t)t * maxTiles + tile];  // global base
  }
  __syncthreads();

  // Phase C: store elements directly at tile-sorted LDS positions
  #pragma unroll
  for (int s = 0; s < SSLOT; ++s){
    int idx = cbase + (s << 6) + lane;
    if (idx < total){
      u32 rd = rrd[s];
      u32 d = rd & (RADIX - 1);
      u32 p = startS[d] + (u32)wh[d] + (rd >> 16);
      stage[p] = relem[s];
    }
  }
  __syncthreads();

  // Phase D: linear LDS read -> coalesced run writes
  int tileElems = total - tbase; if (tileElems > STILE) tileElems = STILE;
  for (int j = t; j < tileElems; j += SCTPB){
    u64 e = stage[j];
    u32 key = (u32)(e >> 32);
    int d = (int)((key >> shift) & (RADIX - 1));
    int dest = (int)(baseS[d] + (u32)j - startS[d]);
    out[dest] = e;
  }
}

// unzip sorted packed buffer + tail fill, uint4 (4-elem) coalesced stores
__global__ void unzipTailK(const u64* __restrict__ buf, int* out_m, int* out_s,
                           const int* total_p, int MT){
  int total = *total_p;
  int base = blockIdx.x * 8192 + threadIdx.x * 4;
  #pragma unroll
  for (int s = 0; s < 8; ++s){
    int j = base + s * 1024;
    if (j + 3 < MT && (j + 3 < total || j >= total)){
      uint4 vm, vsid;
      if (j + 3 < total){
        u64 e0 = buf[j], e1 = buf[j+1], e2 = buf[j+2], e3 = buf[j+3];
        vm   = make_uint4((u32)(e0 >> 32), (u32)(e1 >> 32), (u32)(e2 >> 32), (u32)(e3 >> 32));
        vsid = make_uint4((u32)e0, (u32)e1, (u32)e2, (u32)e3);
      } else {
        vm   = make_uint4(0u, 0u, 0u, 0u);
        vsid = make_uint4(0xFFFFFFFFu, 0xFFFFFFFFu, 0xFFFFFFFFu, 0xFFFFFFFFu);
      }
      *(uint4*)&out_m[j] = vm;
      *(uint4*)&out_s[j] = vsid;
    } else if (j < MT){
      int end = (j + 4 < MT) ? j + 4 : MT;
      for (int k = j; k < end; ++k){
        if (k < total){
          u64 e = buf[k];
          out_m[k] = (int)(u32)(e >> 32);
          out_s[k] = (int)(u32)e;
        } else {
          out_m[k] = 0;
          out_s[k] = -1;
        }
      }
    }
  }
}

extern "C" void kernel_launch(void* const* d_in, const int* in_sizes, int n_in,
                              void* d_out, int out_size, void* d_ws, size_t ws_size,
                              hipStream_t stream){
  const float* mn   = (const float*)d_in[0];
  const float* mx   = (const float*)d_in[1];
  const float* gmin = (const float*)d_in[2];
  const float* vs   = (const float*)d_in[3];
  const int*   gs   = (const int*)d_in[4];
  const int*   T_p  = (const int*)d_in[5];

  int M = in_sizes[0] / 3;
  long long S = (long long)out_size - 2LL*M - 2LL;
  int T = (int)(S / (2LL*M));
  int MT = (int)((long long)M * T);

  int* out_m     = (int*)d_out;
  int* out_s     = out_m + MT;
  int* out_off   = out_s + MT;
  int* out_ovr   = out_off + (M + 1);
  int* out_total = out_ovr + M;

  uint8_t* w = (uint8_t*)d_ws;
  size_t off = 0;
  auto alloc = [&](size_t bytes) -> void* {
    size_t p = (off + 255) & ~(size_t)255;
    off = p + bytes;
    return (void*)(w + p);
  };
  int nbA = (M + TILE - 1) / TILE;
  u32*   counts     = (u32*)alloc((size_t)M * 4);
  uint4* boxEnc     = (uint4*)alloc((size_t)M * 16);
  u32*   blockSums  = (u32*)alloc((size_t)nbA * 4);
  u32*   digitTotal = (u32*)alloc(RADIX * 4);

  size_t fixed = off + 8192;
  size_t avail = ws_size > fixed ? ws_size - fixed : 0;
  long long cap = (long long)(avail / 14) & ~(long long)(STILE - 1);
  if (cap > MT) cap = MT;
  if (cap < STILE) cap = STILE;
  int maxTiles = (int)(cap / STILE);

  size_t histSz = (size_t)RADIX * maxTiles * 4;
  u32* hist0 = (u32*)alloc(histSz);   // memset, then genK accumulates
  u32* hist1 = (u32*)alloc(histSz);   // fully overwritten by histK
  u32* hist2 = (u32*)alloc(histSz);   // fully overwritten by histK
  u64* bufA  = (u64*)alloc((size_t)cap * 8);

  u64* bufB = (u64*)d_out;   // packed u64 region: bytes [0, 8*total) <= 8*MT

  int gM = (M + TPB - 1) / TPB;
  int gGen = (M + GSPB - 1) / GSPB;

  hipMemsetAsync(hist0, 0, histSz, stream);
  countK<<<gM, TPB, 0, stream>>>(mn, mx, gmin, vs, gs, T_p, counts, out_ovr, boxEnc, M);
  scanAK<<<nbA, TPB, 0, stream>>>(counts, out_off, blockSums, M);
  scanBK<<<1, TPB, 0, stream>>>(blockSums, nbA);
  scanCK<<<nbA, TPB, 0, stream>>>(out_off, blockSums, M, out_total);
  genK<<<gGen, TPB, 0, stream>>>(boxEnc, out_off, bufB, hist0, maxTiles, M);

  // pass 0: B(d_out) -> A   (hist0 from genK)
  tileScanK<<<RADIX, TPB, 0, stream>>>(hist0, digitTotal, out_total, maxTiles);
  scatterK<<<maxTiles, SCTPB, 0, stream>>>(bufB, bufA, hist0, digitTotal, out_total, maxTiles, 0);

  // pass 1: A -> B
  histK<<<maxTiles, TPB, 0, stream>>>(bufA, hist1, out_total, maxTiles, RBITS);
  tileScanK<<<RADIX, TPB, 0, stream>>>(hist1, digitTotal, out_total, maxTiles);
  scatterK<<<maxTiles, SCTPB, 0, stream>>>(bufA, bufB, hist1, digitTotal, out_total, maxTiles, RBITS);

  // pass 2: B -> A
  histK<<<maxTiles, TPB, 0, stream>>>(bufB, hist2, out_total, maxTiles, 2*RBITS);
  tileScanK<<<RADIX, TPB, 0, stream>>>(hist2, digitTotal, out_total, maxTiles);
  scatterK<<<maxTiles, SCTPB, 0, stream>>>(bufB, bufA, hist2, digitTotal, out_total, maxTiles, 2*RBITS);

  // unzip + tail fill
  unzipTailK<<<(MT + 8191) / 8192, TPB, 0, stream>>>(bufA, out_m, out_s, out_total, MT);
}

// Round 14
// 410.598 us; speedup vs baseline: 1.1456x; 1.1456x over previous
//
#include <hip/hip_runtime.h>
#include <stdint.h>

typedef uint16_t u16;
typedef uint32_t u32;
typedef uint64_t u64;

#define TPB   256
#define TILE  2048      // scan granularity (TPB*8)
#define RADIX 512
#define RBITS 9
#define STILE 4096      // sort tile (2^12)
#define GSPB  256       // genK spheres per block (2 per wave concurrently)

#define SCTPB 512       // scatter threads (8 waves)
#define NWAVE 8
#define SSLOT 8         // STILE / SCTPB
#define NXCD  8

__device__ __forceinline__ int clampi(int v, int lo, int hi){ return v < lo ? lo : (v > hi ? hi : v); }

__device__ __forceinline__ u32 expand10(u32 x){
  x &= 1023u;
  x = (x | (x << 16)) & 0x030000FFu;
  x = (x | (x << 8))  & 0x0300F00Fu;
  x = (x | (x << 4))  & 0x030C30C3u;
  x = (x | (x << 2))  & 0x09249249u;
  return x;
}

struct Box { int a0,a1,a2,e0,e1,e2,nv; };
__device__ __forceinline__ Box boxOf(int i, const float* mn, const float* mx,
                                     float g0, float g1, float g2, float vs, int gs){
  Box b;
  int a0 = clampi((int)floorf((mn[3*i+0] - g0) / vs), 0, gs-1);
  int a1 = clampi((int)floorf((mn[3*i+1] - g1) / vs), 0, gs-1);
  int a2 = clampi((int)floorf((mn[3*i+2] - g2) / vs), 0, gs-1);
  int b0 = clampi((int)floorf((mx[3*i+0] - g0) / vs), 0, gs-1);
  int b1 = clampi((int)floorf((mx[3*i+1] - g1) / vs), 0, gs-1);
  int b2 = clampi((int)floorf((mx[3*i+2] - g2) / vs), 0, gs-1);
  b.a0=a0; b.a1=a1; b.a2=a2;
  b.e0=b0-a0+1; b.e1=b1-a1+1; b.e2=b2-a2+1;
  b.nv = b.e0*b.e1*b.e2;
  return b;
}

// counts, oversized flags, and packed box encoding with div magics
__global__ void countK(const float* mn, const float* mx, const float* gmin,
                       const float* vs_p, const int* gs_p, const int* T_p,
                       u32* counts, int* out_ovr, uint4* boxEnc, int M){
  int i = blockIdx.x * TPB + threadIdx.x;
  if (i >= M) return;
  float vs = vs_p[0]; int gs = gs_p[0]; int T = T_p[0];
  Box b = boxOf(i, mn, mx, gmin[0], gmin[1], gmin[2], vs, gs);
  int ovr = b.nv > T;
  counts[i] = ovr ? 0u : (u32)b.nv;
  out_ovr[i] = ovr;
  u32 nvq = ovr ? 0u : (u32)b.nv;
  uint4 be;
  be.x = (u32)b.a0 | ((u32)b.a1 << 10) | ((u32)b.a2 << 20);
  be.y = (u32)b.e1 | ((u32)b.e2 << 7) | (nvq << 14);
  be.z = 65535u / (u32)b.e1 + 1u;   // mEy = ceil(2^16/e1)
  be.w = 65535u / (u32)b.e2 + 1u;   // mEz = ceil(2^16/e2)
  boxEnc[i] = be;
}

__global__ void scanAK(const u32* counts, int* out_off, u32* blockSums, int M){
  __shared__ u32 s[TPB];
  int b = blockIdx.x, t = threadIdx.x;
  int base = b * TILE + t * 8;
  u32 incl[8]; u32 run = 0;
  #pragma unroll
  for (int j = 0; j < 8; ++j){
    int g = base + j;
    u32 v = (g < M) ? counts[g] : 0u;
    run += v; incl[j] = run;
  }
  s[t] = run;
  __syncthreads();
  for (int o = 1; o < TPB; o <<= 1){
    u32 x = (t >= o) ? s[t-o] : 0u;
    __syncthreads();
    s[t] += x;
    __syncthreads();
  }
  u32 tbase = s[t] - run;
  #pragma unroll
  for (int j = 0; j < 8; ++j){
    int g = base + j;
    if (g < M) out_off[g+1] = (int)(tbase + incl[j]);
  }
  if (t == TPB-1) blockSums[b] = s[TPB-1];
}

__global__ void scanBK(u32* blockSums, int nb){
  __shared__ u32 s[TPB];
  int t = threadIdx.x;
  u32 run = 0;
  int nch = (nb + TPB - 1) / TPB;
  for (int c = 0; c < nch; ++c){
    int i = c * TPB + t;
    u32 v = (i < nb) ? blockSums[i] : 0u;
    s[t] = v;
    __syncthreads();
    for (int o = 1; o < TPB; o <<= 1){
      u32 x = (t >= o) ? s[t-o] : 0u;
      __syncthreads();
      s[t] += x;
      __syncthreads();
    }
    if (i < nb) blockSums[i] = run + s[t] - v;
    u32 tot = s[TPB-1];
    __syncthreads();
    run += tot;
  }
}

__global__ void scanCK(int* out_off, const u32* blockSums, int M, int* out_total){
  int b = blockIdx.x, t = threadIdx.x;
  u32 add = blockSums[b];
  int base = b * TILE + t * 8;
  #pragma unroll
  for (int j = 0; j < 8; ++j){
    int g = base + j;
    if (g < M){
      int v = out_off[g+1] + (int)add;
      out_off[g+1] = v;
      if (g == M-1) out_total[0] = v;
    }
  }
  if (b == 0 && t == 0) out_off[0] = 0;
}

// pure generator: half-wave (32 lanes) per sphere, zero division, coalesced stores
__global__ void genK(const uint4* __restrict__ boxEnc, const int* __restrict__ out_off,
                     u64* __restrict__ out, int M){
  int t = threadIdx.x;
  int lane = t & 63, wave = t >> 6;
  int half = lane >> 5, l32 = lane & 31;
  int sbase = blockIdx.x * GSPB;
  int slot = wave * 2 + half;          // 0..7
  for (int s0 = 0; s0 < GSPB; s0 += 8){
    int i = sbase + s0 + slot;
    if (i >= M) continue;
    uint4 be = boxEnc[i];
    int nv = (int)(be.y >> 14);
    if (nv == 0) continue;             // oversized or empty
    int ey = (int)(be.y & 127), ez = (int)((be.y >> 7) & 127);
    int a0 = (int)(be.x & 1023), a1 = (int)((be.x >> 10) & 1023), a2 = (int)(be.x >> 20);
    u32 mEy = be.z, mEz = be.w;
    int base = out_off[i];
    for (int k = l32; k < nv; k += 32){
      u32 q1 = ((u32)k * mEz) >> 16;           // k / ez   (exact, k<=63)
      int dz = k - (int)(q1 * (u32)ez);
      u32 q2 = (q1 * mEy) >> 16;               // q1 / ey  (exact)
      int dy = (int)q1 - (int)(q2 * (u32)ey);
      int dx = (int)q2;
      u32 m = (expand10((u32)(a0 + dx)) << 2) |
              (expand10((u32)(a1 + dy)) << 1) |
               expand10((u32)(a2 + dz));
      out[base + k] = ((u64)m << 32) | (u32)i;
    }
  }
}

// per-tile histogram (reads hi words of packed u64, uint4 loads)
__global__ void histK(const u64* __restrict__ in, u32* hist,
                      const int* total_p, int maxTiles, int shift){
  __shared__ u32 cnt[RADIX];
  int tile = blockIdx.x, t = threadIdx.x;
  int total = *total_p;
  int numTiles = (total + STILE - 1) / STILE;
  if (tile >= numTiles) return;
  cnt[t] = 0; cnt[t + TPB] = 0;
  __syncthreads();
  int base = tile * STILE;
  if (base + STILE <= total){
    const uint4* k4 = (const uint4*)(in + base);   // 2 packed elems per uint4
    #pragma unroll
    for (int s = 0; s < 8; ++s){
      uint4 v = k4[s * TPB + t];
      atomicAdd(&cnt[(v.y >> shift) & (RADIX-1)], 1u);
      atomicAdd(&cnt[(v.w >> shift) & (RADIX-1)], 1u);
    }
  } else {
    const u32* hi = (const u32*)in;
    #pragma unroll
    for (int s = 0; s < 16; ++s){
      int j = base + s * TPB + t;
      if (j < total) atomicAdd(&cnt[(hi[2*j+1] >> shift) & (RADIX-1)], 1u);
    }
  }
  __syncthreads();
  for (int d = t; d < RADIX; d += TPB)
    hist[(size_t)d * maxTiles + tile] = cnt[d];
}

// per-digit running prefix over tiles (in place, base 0); emit per-digit total
__global__ void tileScanK(u32* hist, u32* digitTotal, const int* total_p, int maxTiles){
  __shared__ u32 s[TPB];
  int d = blockIdx.x, t = threadIdx.x;
  int total = *total_p;
  int numTiles = (total + STILE - 1) / STILE;
  u32 running = 0;
  int nch = (numTiles + TPB - 1) / TPB;
  for (int c = 0; c < nch; ++c){
    int i = c * TPB + t;
    u32 v = (i < numTiles) ? hist[(size_t)d * maxTiles + i] : 0u;
    s[t] = v;
    __syncthreads();
    for (int o = 1; o < TPB; o <<= 1){
      u32 x = (t >= o) ? s[t-o] : 0u;
      __syncthreads();
      s[t] += x;
      __syncthreads();
    }
    if (i < numTiles) hist[(size_t)d * maxTiles + i] = running + s[t] - v;
    u32 tot = s[TPB-1];
    __syncthreads();
    running += tot;
  }
  if (t == 0) digitTotal[d] = running;
}

// exclusive scan of one 512-digit total array  (launch <<<1, RADIX>>>)
__global__ void digitScanK(const u32* digitTotal, u32* digitBase){
  __shared__ u32 s[RADIX];
  int t = threadIdx.x;
  u32 v = digitTotal[t];
  s[t] = v;
  __syncthreads();
  for (int o = 1; o < RADIX; o <<= 1){
    u32 x = (t >= o) ? s[t-o] : 0u;
    __syncthreads();
    s[t] += x;
    __syncthreads();
  }
  digitBase[t] = s[t] - v;
}

// staged scatter: 8 waves, elements held in registers, direct scattered LDS
// store into tile-sorted stage[], linear LDS read -> coalesced run writes.
// split==0: packed u64 to outP.  split==1: key->outM, sid->outS (final pass).
__global__ __launch_bounds__(SCTPB, 4)
void scatterK(const u64* __restrict__ in, u64* __restrict__ outP,
              u32* __restrict__ outM, u32* __restrict__ outS,
              const u32* __restrict__ hist, const u32* __restrict__ digitBase,
              const int* total_p, int maxTiles, int shift, int split){
  __shared__ u64 stage[STILE];          // 32 KB  tile-sorted elements
  __shared__ u16 wHist[NWAVE * RADIX];  // 8 KB   [wave][digit]
  __shared__ u32 startS[RADIX];         // 2 KB   tile-local exclusive digit starts
  __shared__ u32 baseS[RADIX];          // 2 KB   scan scratch, then global digit bases

  int t = threadIdx.x;
  int total = *total_p;
  int numTiles = (total + STILE - 1) / STILE;

  // bijective XCD-chunked swizzle: consecutive tiles -> same XCD
  int bid = blockIdx.x;
  int q = numTiles / NXCD, r = numTiles % NXCD;
  int x = bid & (NXCD - 1), pos = bid >> 3;
  int cnt_x = q + (x < r ? 1 : 0);
  if (pos >= cnt_x) return;
  int tile = (x < r ? x * (q + 1) : r * (q + 1) + (x - r) * q) + pos;

  int lane = t & 63, wave = t >> 6;
  u64 lt = (1ull << lane) - 1ull;
  u16* wh = &wHist[wave << 9];

  for (int i = t; i < NWAVE * RADIX; i += SCTPB) wHist[i] = 0;
  __syncthreads();

  int tbase = tile * STILE;
  int cbase = tbase + (wave << 9);     // wave-private contiguous chunk of 512
  u64 relem[SSLOT];                    // elements in registers (static indices)
  u32 rrd[SSLOT];                      // (rankInWave<<16) | digit

  // Phase A: load + stable wave rank (order: wave, slot, lane == index order)
  #pragma unroll
  for (int s = 0; s < SSLOT; ++s){
    int idx = cbase + (s << 6) + lane;
    bool valid = idx < total;
    u64 e = valid ? in[idx] : 0ull;
    relem[s] = e;
    int d = (int)(((u32)(e >> 32)) >> shift) & (RADIX - 1);
    u64 mask = __ballot(valid);
    #pragma unroll
    for (int b = 0; b < RBITS; ++b){
      u64 bal = __ballot((d >> b) & 1);
      mask &= ((d >> b) & 1) ? bal : ~bal;
    }
    u32 lr = (u32)__popcll(mask & lt);
    u32 old = valid ? (u32)wh[d] : 0u;
    if (valid && ((mask & lt) == 0ull)) wh[d] = (u16)(old + (u32)__popcll(mask));
    rrd[s] = ((old + lr) << 16) | (u32)d;
  }
  __syncthreads();

  // Phase B1: combine 8 wave hists (thread t <-> digit t; SCTPB == RADIX)
  {
    int d = t;
    u32 run = 0;
    #pragma unroll
    for (int wv = 0; wv < NWAVE; ++wv){
      u32 cc = wHist[(wv << 9) + d];
      wHist[(wv << 9) + d] = (u16)run;
      run += cc;
    }
    startS[d] = run;
  }
  __syncthreads();

  // Phase B2: exclusive scan of startS (scratch = baseS), then load global bases
  {
    u32 v = startS[t];
    baseS[t] = v;
    __syncthreads();
    for (int o = 1; o < RADIX; o <<= 1){
      u32 xv = (t >= o) ? baseS[t-o] : 0u;
      __syncthreads();
      baseS[t] += xv;
      __syncthreads();
    }
    u32 excl = baseS[t] - v;
    __syncthreads();
    startS[t] = excl;
    baseS[t] = digitBase[t] + hist[(size_t)t * maxTiles + tile];
  }
  __syncthreads();

  // Phase C: store elements directly at tile-sorted LDS positions
  #pragma unroll
  for (int s = 0; s < SSLOT; ++s){
    int idx = cbase + (s << 6) + lane;
    if (idx < total){
      u32 rd = rrd[s];
      u32 d = rd & (RADIX - 1);
      u32 p = startS[d] + (u32)wh[d] + (rd >> 16);
      stage[p] = relem[s];
    }
  }
  __syncthreads();

  // Phase D: linear LDS read -> coalesced run writes
  int tileElems = total - tbase; if (tileElems > STILE) tileElems = STILE;
  if (split){
    for (int j = t; j < tileElems; j += SCTPB){
      u64 e = stage[j];
      u32 key = (u32)(e >> 32);
      int d = (int)((key >> shift) & (RADIX - 1));
      int dest = (int)(baseS[d] + (u32)j - startS[d]);
      outM[dest] = key;
      outS[dest] = (u32)e;
    }
  } else {
    for (int j = t; j < tileElems; j += SCTPB){
      u64 e = stage[j];
      u32 key = (u32)(e >> 32);
      int d = (int)((key >> shift) & (RADIX - 1));
      int dest = (int)(baseS[d] + (u32)j - startS[d]);
      outP[dest] = e;
    }
  }
}

// tail fill: out_m[j]=0, out_s[j]=-1 for j in [total, MT), uint4 vectorized
__global__ void tailK(int* out_m, int* out_s, const int* total_p, int MT){
  int total = *total_p;
  int j = (blockIdx.x * TPB + threadIdx.x) * 4;
  if (j >= MT) return;
  if (j >= total){
    if (j + 3 < MT){
      *(uint4*)&out_m[j] = make_uint4(0u, 0u, 0u, 0u);
      *(uint4*)&out_s[j] = make_uint4(0xFFFFFFFFu, 0xFFFFFFFFu, 0xFFFFFFFFu, 0xFFFFFFFFu);
    } else {
      for (int k = j; k < MT; ++k){ out_m[k] = 0; out_s[k] = -1; }
    }
  } else if (j + 4 > total){
    int end = (j + 4 < MT) ? j + 4 : MT;
    for (int k = total; k < end; ++k){ out_m[k] = 0; out_s[k] = -1; }
  }
}

extern "C" void kernel_launch(void* const* d_in, const int* in_sizes, int n_in,
                              void* d_out, int out_size, void* d_ws, size_t ws_size,
                              hipStream_t stream){
  const float* mn   = (const float*)d_in[0];
  const float* mx   = (const float*)d_in[1];
  const float* gmin = (const float*)d_in[2];
  const float* vs   = (const float*)d_in[3];
  const int*   gs   = (const int*)d_in[4];
  const int*   T_p  = (const int*)d_in[5];

  int M = in_sizes[0] / 3;
  long long S = (long long)out_size - 2LL*M - 2LL;
  int T = (int)(S / (2LL*M));
  int MT = (int)((long long)M * T);

  int* out_m     = (int*)d_out;
  int* out_s     = out_m + MT;
  int* out_off   = out_s + MT;
  int* out_ovr   = out_off + (M + 1);
  int* out_total = out_ovr + M;

  uint8_t* w = (uint8_t*)d_ws;
  size_t off = 0;
  auto alloc = [&](size_t bytes) -> void* {
    size_t p = (off + 255) & ~(size_t)255;
    off = p + bytes;
    return (void*)(w + p);
  };
  int nbA = (M + TILE - 1) / TILE;
  u32*   counts     = (u32*)alloc((size_t)M * 4);
  uint4* boxEnc     = (uint4*)alloc((size_t)M * 16);
  u32*   blockSums  = (u32*)alloc((size_t)nbA * 4);
  u32*   digitTotal = (u32*)alloc(RADIX * 4);
  u32*   digitBase  = (u32*)alloc(RADIX * 4);

  size_t fixed = off + 8192;
  size_t avail = ws_size > fixed ? ws_size - fixed : 0;
  long long cap = (long long)(avail / 14) & ~(long long)(STILE - 1);
  if (cap > MT) cap = MT;
  if (cap < STILE) cap = STILE;
  int maxTiles = (int)(cap / STILE);

  size_t histSz = (size_t)RADIX * maxTiles * 4;
  u32* hist0 = (u32*)alloc(histSz);   // fully overwritten by histK
  u32* hist1 = (u32*)alloc(histSz);   // fully overwritten by histK
  u32* hist2 = (u32*)alloc(histSz);   // fully overwritten by histK
  u64* bufA  = (u64*)alloc((size_t)cap * 8);   // in ws

  u64* bufB = (u64*)d_out;   // packed u64 region: bytes [0, 8*total) <= 8*MT

  int gM = (M + TPB - 1) / TPB;
  int gGen = (M + GSPB - 1) / GSPB;

  countK<<<gM, TPB, 0, stream>>>(mn, mx, gmin, vs, gs, T_p, counts, out_ovr, boxEnc, M);
  scanAK<<<nbA, TPB, 0, stream>>>(counts, out_off, blockSums, M);
  scanBK<<<1, TPB, 0, stream>>>(blockSums, nbA);
  scanCK<<<nbA, TPB, 0, stream>>>(out_off, blockSums, M, out_total);
  genK<<<gGen, TPB, 0, stream>>>(boxEnc, out_off, bufA, M);

  // pass 0: A(ws) -> B(d_out)
  histK<<<maxTiles, TPB, 0, stream>>>(bufA, hist0, out_total, maxTiles, 0);
  tileScanK<<<RADIX, TPB, 0, stream>>>(hist0, digitTotal, out_total, maxTiles);
  digitScanK<<<1, RADIX, 0, stream>>>(digitTotal, digitBase);
  scatterK<<<maxTiles, SCTPB, 0, stream>>>(bufA, bufB, nullptr, nullptr, hist0, digitBase, out_total, maxTiles, 0, 0);

  // pass 1: B -> A
  histK<<<maxTiles, TPB, 0, stream>>>(bufB, hist1, out_total, maxTiles, RBITS);
  tileScanK<<<RADIX, TPB, 0, stream>>>(hist1, digitTotal, out_total, maxTiles);
  digitScanK<<<1, RADIX, 0, stream>>>(digitTotal, digitBase);
  scatterK<<<maxTiles, SCTPB, 0, stream>>>(bufB, bufA, nullptr, nullptr, hist1, digitBase, out_total, maxTiles, RBITS, 0);

  // tail fill (after last read of bufB, which aliases out_m/out_s regions)
  tailK<<<(MT/4 + TPB - 1) / TPB, TPB, 0, stream>>>(out_m, out_s, out_total, MT);

  // pass 2: A -> split outputs (out_m, out_s) directly; valid region [0, total)
  histK<<<maxTiles, TPB, 0, stream>>>(bufA, hist2, out_total, maxTiles, 2*RBITS);
  tileScanK<<<RADIX, TPB, 0, stream>>>(hist2, digitTotal, out_total, maxTiles);
  digitScanK<<<1, RADIX, 0, stream>>>(digitTotal, digitBase);
  scatterK<<<maxTiles, SCTPB, 0, stream>>>(bufA, nullptr, (u32*)out_m, (u32*)out_s, hist2, digitBase, out_total, maxTiles, 2*RBITS, 1);
}

// Round 15
// 379.524 us; speedup vs baseline: 1.2394x; 1.0819x over previous
//
#include <hip/hip_runtime.h>
#include <stdint.h>

typedef uint16_t u16;
typedef uint32_t u32;
typedef uint64_t u64;

#define TPB   256
#define TILE  2048      // scan granularity (TPB*8)
#define RADIX 512
#define RBITS 9
#define STILE 8192      // sort tile (2^13)
#define GSPB  256       // genK spheres per block (2 per wave concurrently)

#define SCTPB 512       // scatter threads (8 waves)
#define NWAVE 8
#define SSLOT 16        // STILE / SCTPB
#define NXCD  8

__device__ __forceinline__ int clampi(int v, int lo, int hi){ return v < lo ? lo : (v > hi ? hi : v); }

__device__ __forceinline__ u32 expand10(u32 x){
  x &= 1023u;
  x = (x | (x << 16)) & 0x030000FFu;
  x = (x | (x << 8))  & 0x0300F00Fu;
  x = (x | (x << 4))  & 0x030C30C3u;
  x = (x | (x << 2))  & 0x09249249u;
  return x;
}

struct Box { int a0,a1,a2,e0,e1,e2,nv; };
__device__ __forceinline__ Box boxOf(int i, const float* mn, const float* mx,
                                     float g0, float g1, float g2, float vs, int gs){
  Box b;
  int a0 = clampi((int)floorf((mn[3*i+0] - g0) / vs), 0, gs-1);
  int a1 = clampi((int)floorf((mn[3*i+1] - g1) / vs), 0, gs-1);
  int a2 = clampi((int)floorf((mn[3*i+2] - g2) / vs), 0, gs-1);
  int b0 = clampi((int)floorf((mx[3*i+0] - g0) / vs), 0, gs-1);
  int b1 = clampi((int)floorf((mx[3*i+1] - g1) / vs), 0, gs-1);
  int b2 = clampi((int)floorf((mx[3*i+2] - g2) / vs), 0, gs-1);
  b.a0=a0; b.a1=a1; b.a2=a2;
  b.e0=b0-a0+1; b.e1=b1-a1+1; b.e2=b2-a2+1;
  b.nv = b.e0*b.e1*b.e2;
  return b;
}

// counts, oversized flags, and packed box encoding with div magics
__global__ void countK(const float* mn, const float* mx, const float* gmin,
                       const float* vs_p, const int* gs_p, const int* T_p,
                       u32* counts, int* out_ovr, uint4* boxEnc, int M){
  int i = blockIdx.x * TPB + threadIdx.x;
  if (i >= M) return;
  float vs = vs_p[0]; int gs = gs_p[0]; int T = T_p[0];
  Box b = boxOf(i, mn, mx, gmin[0], gmin[1], gmin[2], vs, gs);
  int ovr = b.nv > T;
  counts[i] = ovr ? 0u : (u32)b.nv;
  out_ovr[i] = ovr;
  u32 nvq = ovr ? 0u : (u32)b.nv;
  uint4 be;
  be.x = (u32)b.a0 | ((u32)b.a1 << 10) | ((u32)b.a2 << 20);
  be.y = (u32)b.e1 | ((u32)b.e2 << 7) | (nvq << 14);
  be.z = 65535u / (u32)b.e1 + 1u;   // mEy = ceil(2^16/e1)
  be.w = 65535u / (u32)b.e2 + 1u;   // mEz = ceil(2^16/e2)
  boxEnc[i] = be;
}

__global__ void scanAK(const u32* counts, int* out_off, u32* blockSums, int M){
  __shared__ u32 s[TPB];
  int b = blockIdx.x, t = threadIdx.x;
  int base = b * TILE + t * 8;
  u32 incl[8]; u32 run = 0;
  #pragma unroll
  for (int j = 0; j < 8; ++j){
    int g = base + j;
    u32 v = (g < M) ? counts[g] : 0u;
    run += v; incl[j] = run;
  }
  s[t] = run;
  __syncthreads();
  for (int o = 1; o < TPB; o <<= 1){
    u32 x = (t >= o) ? s[t-o] : 0u;
    __syncthreads();
    s[t] += x;
    __syncthreads();
  }
  u32 tbase = s[t] - run;
  #pragma unroll
  for (int j = 0; j < 8; ++j){
    int g = base + j;
    if (g < M) out_off[g+1] = (int)(tbase + incl[j]);
  }
  if (t == TPB-1) blockSums[b] = s[TPB-1];
}

__global__ void scanBK(u32* blockSums, int nb){
  __shared__ u32 s[TPB];
  int t = threadIdx.x;
  u32 run = 0;
  int nch = (nb + TPB - 1) / TPB;
  for (int c = 0; c < nch; ++c){
    int i = c * TPB + t;
    u32 v = (i < nb) ? blockSums[i] : 0u;
    s[t] = v;
    __syncthreads();
    for (int o = 1; o < TPB; o <<= 1){
      u32 x = (t >= o) ? s[t-o] : 0u;
      __syncthreads();
      s[t] += x;
      __syncthreads();
    }
    if (i < nb) blockSums[i] = run + s[t] - v;
    u32 tot = s[TPB-1];
    __syncthreads();
    run += tot;
  }
}

__global__ void scanCK(int* out_off, const u32* blockSums, int M, int* out_total){
  int b = blockIdx.x, t = threadIdx.x;
  u32 add = blockSums[b];
  int base = b * TILE + t * 8;
  #pragma unroll
  for (int j = 0; j < 8; ++j){
    int g = base + j;
    if (g < M){
      int v = out_off[g+1] + (int)add;
      out_off[g+1] = v;
      if (g == M-1) out_total[0] = v;
    }
  }
  if (b == 0 && t == 0) out_off[0] = 0;
}

// pure generator: half-wave (32 lanes) per sphere, zero division, coalesced stores
__global__ void genK(const uint4* __restrict__ boxEnc, const int* __restrict__ out_off,
                     u64* __restrict__ out, int M){
  int t = threadIdx.x;
  int lane = t & 63, wave = t >> 6;
  int half = lane >> 5, l32 = lane & 31;
  int sbase = blockIdx.x * GSPB;
  int slot = wave * 2 + half;          // 0..7
  for (int s0 = 0; s0 < GSPB; s0 += 8){
    int i = sbase + s0 + slot;
    if (i >= M) continue;
    uint4 be = boxEnc[i];
    int nv = (int)(be.y >> 14);
    if (nv == 0) continue;             // oversized or empty
    int ey = (int)(be.y & 127), ez = (int)((be.y >> 7) & 127);
    int a0 = (int)(be.x & 1023), a1 = (int)((be.x >> 10) & 1023), a2 = (int)(be.x >> 20);
    u32 mEy = be.z, mEz = be.w;
    int base = out_off[i];
    for (int k = l32; k < nv; k += 32){
      u32 q1 = ((u32)k * mEz) >> 16;           // k / ez   (exact, k<=63)
      int dz = k - (int)(q1 * (u32)ez);
      u32 q2 = (q1 * mEy) >> 16;               // q1 / ey  (exact)
      int dy = (int)q1 - (int)(q2 * (u32)ey);
      int dx = (int)q2;
      u32 m = (expand10((u32)(a0 + dx)) << 2) |
              (expand10((u32)(a1 + dy)) << 1) |
               expand10((u32)(a2 + dz));
      out[base + k] = ((u64)m << 32) | (u32)i;
    }
  }
}

// per-tile histogram (reads hi words of packed u64, uint4 loads)
__global__ void histK(const u64* __restrict__ in, u32* hist,
                      const int* total_p, int maxTiles, int shift){
  __shared__ u32 cnt[RADIX];
  int tile = blockIdx.x, t = threadIdx.x;
  int total = *total_p;
  int numTiles = (total + STILE - 1) / STILE;
  if (tile >= numTiles) return;
  cnt[t] = 0; cnt[t + TPB] = 0;
  __syncthreads();
  int base = tile * STILE;
  if (base + STILE <= total){
    const uint4* k4 = (const uint4*)(in + base);   // 2 packed elems per uint4
    #pragma unroll
    for (int s = 0; s < STILE / (2 * TPB); ++s){
      uint4 v = k4[s * TPB + t];
      atomicAdd(&cnt[(v.y >> shift) & (RADIX-1)], 1u);
      atomicAdd(&cnt[(v.w >> shift) & (RADIX-1)], 1u);
    }
  } else {
    const u32* hi = (const u32*)in;
    #pragma unroll
    for (int s = 0; s < STILE / TPB; ++s){
      int j = base + s * TPB + t;
      if (j < total) atomicAdd(&cnt[(hi[2*j+1] >> shift) & (RADIX-1)], 1u);
    }
  }
  __syncthreads();
  for (int d = t; d < RADIX; d += TPB)
    hist[(size_t)d * maxTiles + tile] = cnt[d];
}

// per-digit running prefix over tiles (in place, base 0); emit per-digit total
__global__ void tileScanK(u32* hist, u32* digitTotal, const int* total_p, int maxTiles){
  __shared__ u32 s[TPB];
  int d = blockIdx.x, t = threadIdx.x;
  int total = *total_p;
  int numTiles = (total + STILE - 1) / STILE;
  u32 running = 0;
  int nch = (numTiles + TPB - 1) / TPB;
  for (int c = 0; c < nch; ++c){
    int i = c * TPB + t;
    u32 v = (i < numTiles) ? hist[(size_t)d * maxTiles + i] : 0u;
    s[t] = v;
    __syncthreads();
    for (int o = 1; o < TPB; o <<= 1){
      u32 x = (t >= o) ? s[t-o] : 0u;
      __syncthreads();
      s[t] += x;
      __syncthreads();
    }
    if (i < numTiles) hist[(size_t)d * maxTiles + i] = running + s[t] - v;
    u32 tot = s[TPB-1];
    __syncthreads();
    running += tot;
  }
  if (t == 0) digitTotal[d] = running;
}

// exclusive scan of one 512-digit total array  (launch <<<1, RADIX>>>)
__global__ void digitScanK(const u32* digitTotal, u32* digitBase){
  __shared__ u32 s[RADIX];
  int t = threadIdx.x;
  u32 v = digitTotal[t];
  s[t] = v;
  __syncthreads();
  for (int o = 1; o < RADIX; o <<= 1){
    u32 x = (t >= o) ? s[t-o] : 0u;
    __syncthreads();
    s[t] += x;
    __syncthreads();
  }
  digitBase[t] = s[t] - v;
}

// staged scatter: 8 waves, elements held in registers, direct scattered LDS
// store into tile-sorted stage[], linear LDS read -> coalesced run writes.
// split==0: packed u64 to outP.  split==1: key->outM, sid->outS (final pass).
__global__ __launch_bounds__(SCTPB, 4)
void scatterK(const u64* __restrict__ in, u64* __restrict__ outP,
              u32* __restrict__ outM, u32* __restrict__ outS,
              const u32* __restrict__ hist, const u32* __restrict__ digitBase,
              const int* total_p, int maxTiles, int shift, int split){
  __shared__ u64 stage[STILE];          // 64 KB  tile-sorted elements
  __shared__ u16 wHist[NWAVE * RADIX];  // 8 KB   [wave][digit]
  __shared__ u32 startS[RADIX];         // 2 KB   tile-local exclusive digit starts
  __shared__ u32 baseS[RADIX];          // 2 KB   scan scratch, then global digit bases

  int t = threadIdx.x;
  int total = *total_p;
  int numTiles = (total + STILE - 1) / STILE;

  // bijective XCD-chunked swizzle: consecutive tiles -> same XCD
  int bid = blockIdx.x;
  int q = numTiles / NXCD, r = numTiles % NXCD;
  int x = bid & (NXCD - 1), pos = bid >> 3;
  int cnt_x = q + (x < r ? 1 : 0);
  if (pos >= cnt_x) return;
  int tile = (x < r ? x * (q + 1) : r * (q + 1) + (x - r) * q) + pos;

  int lane = t & 63, wave = t >> 6;
  u64 lt = (1ull << lane) - 1ull;
  u16* wh = &wHist[wave << 9];

  for (int i = t; i < NWAVE * RADIX; i += SCTPB) wHist[i] = 0;
  __syncthreads();

  int tbase = tile * STILE;
  int cbase = tbase + (wave << 10);    // wave-private contiguous chunk of 1024
  u64 relem[SSLOT];                    // elements in registers (static indices)
  u32 rrd[SSLOT];                      // (rankInWave<<16) | digit

  // Phase A: load + stable wave rank (order: wave, slot, lane == index order)
  #pragma unroll
  for (int s = 0; s < SSLOT; ++s){
    int idx = cbase + (s << 6) + lane;
    bool valid = idx < total;
    u64 e = valid ? in[idx] : 0ull;
    relem[s] = e;
    int d = (int)(((u32)(e >> 32)) >> shift) & (RADIX - 1);
    u64 mask = __ballot(valid);
    #pragma unroll
    for (int b = 0; b < RBITS; ++b){
      u64 bal = __ballot((d >> b) & 1);
      mask &= ((d >> b) & 1) ? bal : ~bal;
    }
    u32 lr = (u32)__popcll(mask & lt);
    u32 old = valid ? (u32)wh[d] : 0u;
    if (valid && ((mask & lt) == 0ull)) wh[d] = (u16)(old + (u32)__popcll(mask));
    rrd[s] = ((old + lr) << 16) | (u32)d;
  }
  __syncthreads();

  // Phase B1: combine 8 wave hists (thread t <-> digit t; SCTPB == RADIX)
  {
    int d = t;
    u32 run = 0;
    #pragma unroll
    for (int wv = 0; wv < NWAVE; ++wv){
      u32 cc = wHist[(wv << 9) + d];
      wHist[(wv << 9) + d] = (u16)run;
      run += cc;
    }
    startS[d] = run;
  }
  __syncthreads();

  // Phase B2: exclusive scan of startS (scratch = baseS), then load global bases
  {
    u32 v = startS[t];
    baseS[t] = v;
    __syncthreads();
    for (int o = 1; o < RADIX; o <<= 1){
      u32 xv = (t >= o) ? baseS[t-o] : 0u;
      __syncthreads();
      baseS[t] += xv;
      __syncthreads();
    }
    u32 excl = baseS[t] - v;
    __syncthreads();
    startS[t] = excl;
    baseS[t] = digitBase[t] + hist[(size_t)t * maxTiles + tile];
  }
  __syncthreads();

  // Phase C: store elements directly at tile-sorted LDS positions
  #pragma unroll
  for (int s = 0; s < SSLOT; ++s){
    int idx = cbase + (s << 6) + lane;
    if (idx < total){
      u32 rd = rrd[s];
      u32 d = rd & (RADIX - 1);
      u32 p = startS[d] + (u32)wh[d] + (rd >> 16);
      stage[p] = relem[s];
    }
  }
  __syncthreads();

  // Phase D: linear LDS read -> coalesced run writes
  int tileElems = total - tbase; if (tileElems > STILE) tileElems = STILE;
  if (split){
    for (int j = t; j < tileElems; j += SCTPB){
      u64 e = stage[j];
      u32 key = (u32)(e >> 32);
      int d = (int)((key >> shift) & (RADIX - 1));
      int dest = (int)(baseS[d] + (u32)j - startS[d]);
      outM[dest] = key;
      outS[dest] = (u32)e;
    }
  } else {
    for (int j = t; j < tileElems; j += SCTPB){
      u64 e = stage[j];
      u32 key = (u32)(e >> 32);
      int d = (int)((key >> shift) & (RADIX - 1));
      int dest = (int)(baseS[d] + (u32)j - startS[d]);
      outP[dest] = e;
    }
  }
}

// tail fill: out_m[j]=0, out_s[j]=-1 for j in [total, MT), uint4 vectorized
__global__ void tailK(int* out_m, int* out_s, const int* total_p, int MT){
  int total = *total_p;
  int j = (blockIdx.x * TPB + threadIdx.x) * 4;
  if (j >= MT) return;
  if (j >= total){
    if (j + 3 < MT){
      *(uint4*)&out_m[j] = make_uint4(0u, 0u, 0u, 0u);
      *(uint4*)&out_s[j] = make_uint4(0xFFFFFFFFu, 0xFFFFFFFFu, 0xFFFFFFFFu, 0xFFFFFFFFu);
    } else {
      for (int k = j; k < MT; ++k){ out_m[k] = 0; out_s[k] = -1; }
    }
  } else if (j + 4 > total){
    int end = (j + 4 < MT) ? j + 4 : MT;
    for (int k = total; k < end; ++k){ out_m[k] = 0; out_s[k] = -1; }
  }
}

extern "C" void kernel_launch(void* const* d_in, const int* in_sizes, int n_in,
                              void* d_out, int out_size, void* d_ws, size_t ws_size,
                              hipStream_t stream){
  const float* mn   = (const float*)d_in[0];
  const float* mx   = (const float*)d_in[1];
  const float* gmin = (const float*)d_in[2];
  const float* vs   = (const float*)d_in[3];
  const int*   gs   = (const int*)d_in[4];
  const int*   T_p  = (const int*)d_in[5];

  int M = in_sizes[0] / 3;
  long long S = (long long)out_size - 2LL*M - 2LL;
  int T = (int)(S / (2LL*M));
  int MT = (int)((long long)M * T);

  int* out_m     = (int*)d_out;
  int* out_s     = out_m + MT;
  int* out_off   = out_s + MT;
  int* out_ovr   = out_off + (M + 1);
  int* out_total = out_ovr + M;

  uint8_t* w = (uint8_t*)d_ws;
  size_t off = 0;
  auto alloc = [&](size_t bytes) -> void* {
    size_t p = (off + 255) & ~(size_t)255;
    off = p + bytes;
    return (void*)(w + p);
  };
  int nbA = (M + TILE - 1) / TILE;
  u32*   counts     = (u32*)alloc((size_t)M * 4);
  uint4* boxEnc     = (uint4*)alloc((size_t)M * 16);
  u32*   blockSums  = (u32*)alloc((size_t)nbA * 4);
  u32*   digitTotal = (u32*)alloc(RADIX * 4);
  u32*   digitBase  = (u32*)alloc(RADIX * 4);

  size_t fixed = off + 8192;
  size_t avail = ws_size > fixed ? ws_size - fixed : 0;
  long long cap = (long long)(avail / 14) & ~(long long)(STILE - 1);
  if (cap > MT) cap = MT;
  if (cap < STILE) cap = STILE;
  int maxTiles = (int)((cap + STILE - 1) / STILE);

  size_t histSz = (size_t)RADIX * maxTiles * 4;
  u32* hist0 = (u32*)alloc(histSz);   // fully overwritten by histK
  u32* hist1 = (u32*)alloc(histSz);   // fully overwritten by histK
  u32* hist2 = (u32*)alloc(histSz);   // fully overwritten by histK
  u64* bufA  = (u64*)alloc((size_t)maxTiles * STILE * 8);   // in ws

  u64* bufB = (u64*)d_out;   // packed u64 region: bytes [0, 8*total) <= 8*MT

  int gM = (M + TPB - 1) / TPB;
  int gGen = (M + GSPB - 1) / GSPB;

  countK<<<gM, TPB, 0, stream>>>(mn, mx, gmin, vs, gs, T_p, counts, out_ovr, boxEnc, M);
  scanAK<<<nbA, TPB, 0, stream>>>(counts, out_off, blockSums, M);
  scanBK<<<1, TPB, 0, stream>>>(blockSums, nbA);
  scanCK<<<nbA, TPB, 0, stream>>>(out_off, blockSums, M, out_total);
  genK<<<gGen, TPB, 0, stream>>>(boxEnc, out_off, bufA, M);

  // pass 0: A(ws) -> B(d_out)
  histK<<<maxTiles, TPB, 0, stream>>>(bufA, hist0, out_total, maxTiles, 0);
  tileScanK<<<RADIX, TPB, 0, stream>>>(hist0, digitTotal, out_total, maxTiles);
  digitScanK<<<1, RADIX, 0, stream>>>(digitTotal, digitBase);
  scatterK<<<maxTiles, SCTPB, 0, stream>>>(bufA, bufB, nullptr, nullptr, hist0, digitBase, out_total, maxTiles, 0, 0);

  // pass 1: B -> A
  histK<<<maxTiles, TPB, 0, stream>>>(bufB, hist1, out_total, maxTiles, RBITS);
  tileScanK<<<RADIX, TPB, 0, stream>>>(hist1, digitTotal, out_total, maxTiles);
  digitScanK<<<1, RADIX, 0, stream>>>(digitTotal, digitBase);
  scatterK<<<maxTiles, SCTPB, 0, stream>>>(bufB, bufA, nullptr, nullptr, hist1, digitBase, out_total, maxTiles, RBITS, 0);

  // tail fill (after last read of bufB, which aliases out_m/out_s regions)
  tailK<<<(MT/4 + TPB - 1) / TPB, TPB, 0, stream>>>(out_m, out_s, out_total, MT);

  // pass 2: A -> split outputs (out_m, out_s) directly; valid region [0, total)
  histK<<<maxTiles, TPB, 0, stream>>>(bufA, hist2, out_total, maxTiles, 2*RBITS);
  tileScanK<<<RADIX, TPB, 0, stream>>>(hist2, digitTotal, out_total, maxTiles);
  digitScanK<<<1, RADIX, 0, stream>>>(digitTotal, digitBase);
  scatterK<<<maxTiles, SCTPB, 0, stream>>>(bufA, nullptr, (u32*)out_m, (u32*)out_s, hist2, digitBase, out_total, maxTiles, 2*RBITS, 1);
}